// Round 5
// baseline (258.812 us; speedup 1.0000x reference)
//
#include <hip/hip_runtime.h>

// Conv3d(8->32, k=3, VALID) + bias + HardSwish + GroupNorm(4) + mean pool.
// R8 (resubmit x2; GPU acquisition timed out both prior rounds, never measured):
// R7 was latency-bound (all pipes <18%): 112 VGPRs of 32x32 A-fragments
// overflowed the 128-reg tier -> compiler re-streamed weights inside the tile
// loop. Fix: 16x16x32 MFMA with co SPLIT ACROSS WAVES (8 waves = 4z x 2coh):
//  - A-table = 7 chunks x 2 (hi/lo) x 4 regs = 56 VGPRs, resident
//  - ~100 VGPR total -> 4 waves/SIMD, 16 waves/CU (2 blocks x 8 waves, 48KB LDS)
//  - B fragment: K=32 = 4 taps x 8 ci, quarter kq -> tap 4c+kq, lane reads 8 ci
//    at one tap = one contiguous ds_read_b128 (same property as R7)
//  - full unroll 8y x 3xt: LDS addresses fold into offset: immediates
//  - epilogue: 32 shuffles (was 160); pack_weights also zeroes ws (no memset)

#define IN 48
#define IN2 2304
#define IN3 110592
#define OUTD 46
#define RS 200            // row stride in dwords (48*4 used + 8 pad for masked overread)
#define NROW 60           // 6 z-rows x 10 y-rows
#define WPK_OFF 1024      // dword offset of packed-weight table inside ws

typedef short v8s    __attribute__((ext_vector_type(8)));
typedef float f32x4  __attribute__((ext_vector_type(4)));
typedef int   i32x4  __attribute__((ext_vector_type(4)));

__device__ __forceinline__ unsigned short f2bf(float f) {
    unsigned u = __builtin_bit_cast(unsigned, f);
    return (unsigned short)((u + 0x7fffu + ((u >> 16) & 1u)) >> 16);   // RNE
}
__device__ __forceinline__ float bf2f(unsigned short h) {
    unsigned u = ((unsigned)h) << 16;
    return __builtin_bit_cast(float, u);
}

// A fragments for 16x16x32, co-split. Layout: [coh][hl][c 0..6][lane][4 dw].
// Lane: co_local = lane&15, kq = lane>>4 -> tap tau = 4c+kq; dword j = ci pair
// (2j lo, 2j+1 hi). tau>=27 -> zero. Also zeroes ws1/ws2 (gid<1024).
__global__ __launch_bounds__(256) void pack_weights(
    const float* __restrict__ w, unsigned* __restrict__ wpk,
    float* __restrict__ wsz)
{
    int gid = blockIdx.x * 256 + threadIdx.x;
    if (gid < 1024) wsz[gid] = 0.f;
    if (gid >= 1792) return;
    int lane = gid & 63;
    int rest = gid >> 6;          // 0..27
    int c   = rest % 7;
    int hl  = (rest / 7) & 1;     // 0 = hi bf16, 1 = lo (residual)
    int coh = rest / 14;
    int n = lane & 15, kq = lane >> 4;
    int co  = coh * 16 + n;
    int tau = 4 * c + kq;
    unsigned o[4];
    #pragma unroll
    for (int j = 0; j < 4; ++j) {
        if (tau >= 27) { o[j] = 0u; continue; }
        float w0 = w[(co * 8 + 2 * j) * 27 + tau];
        float w1 = w[(co * 8 + 2 * j + 1) * 27 + tau];
        unsigned short b0 = f2bf(w0), b1 = f2bf(w1);
        if (hl) {
            b0 = f2bf(w0 - bf2f(b0));
            b1 = f2bf(w1 - bf2f(b1));
        }
        o[j] = ((unsigned)b1 << 16) | b0;
    }
    *(i32x4*)(wpk + (((coh * 2 + hl) * 7 + c) * 64 + lane) * 4) =
        (i32x4){(int)o[0], (int)o[1], (int)o[2], (int)o[3]};
}

__global__ __launch_bounds__(512, 4) void conv_hs_mfma(
    const float* __restrict__ x, const unsigned* __restrict__ wpk,
    const float* __restrict__ bias, float* __restrict__ ws1, float* __restrict__ ws2)
{
    __shared__ unsigned xdw[NROW * RS];   // 48 KB: [row 60][e*4 + cipair] linear
    __shared__ float s1b[32], s2b[32];

    const int tid  = threadIdx.x;
    const int lane = tid & 63;
    const int wv   = tid >> 6;          // 0..7
    const int zw   = wv & 3;            // z offset within tile
    const int coh  = wv >> 2;           // co half (0: co 0-15, 1: co 16-31)
    const int n    = lane & 15;         // A row (co_local) / B col (x)
    const int kq   = lane >> 4;         // k-quarter -> tap 4c+kq

    const int blk = blockIdx.x;
    const int b   = blk / 72;
    const int r0  = blk - b * 72;
    const int zb  = r0 / 6;
    const int yb  = r0 - zb * 6;
    const int z0  = zb * 4, y0 = yb * 8;
    const int z   = z0 + zw;

    if (tid < 32)      s1b[tid] = 0.f;
    else if (tid < 64) s2b[tid - 32] = 0.f;

    // A fragments: 14 coalesced 16B loads; 56 VGPRs, stay resident.
    i32x4 Ah[7], Al[7];
    #pragma unroll
    for (int c = 0; c < 7; ++c) {
        Ah[c] = *(const i32x4*)(wpk + (((coh * 2 + 0) * 7 + c) * 64 + lane) * 4);
        Al[c] = *(const i32x4*)(wpk + (((coh * 2 + 1) * 7 + c) * 64 + lane) * 4);
    }

    // C/D layout (16x16): col = n, row(co_local) = kq*4 + i
    float bias_r[4];
    #pragma unroll
    for (int i = 0; i < 4; ++i)
        bias_r[i] = bias[coh * 16 + kq * 4 + i];

    // Per-lane LDS base per chunk: tau = min(4c+kq, 26) (pad slot -> A=0).
    const char* bc[7];
    #pragma unroll
    for (int c = 0; c < 7; ++c) {
        int tau = 4 * c + kq; if (tau > 26) tau = 26;
        const int toff = ((tau / 9) * 10 + ((tau % 9) / 3)) * (RS * 4)
                       + (tau % 3) * 16;
        bc[c] = (const char*)xdw + zw * (10 * RS * 4) + n * 16 + toff;
    }

    // ---- stage x tile, bf16 ci-pair packed, linear layout ----
    {
        const int q  = tid & 3;
        const int zh = (tid >> 2) & 1;
        const int e  = tid >> 3;          // 0..63, active < 48
        if (e < 48) {
            const float* p0 = x + (b * 8 + 2 * q) * IN3 + e;
            const float* p1 = p0 + IN3;
            unsigned* dst = xdw + e * 4 + q;
            #pragma unroll
            for (int zr2 = 0; zr2 < 3; ++zr2) {
                const int zr = zh * 3 + zr2;
                const int gz = min(z0 + zr, IN - 1);
                #pragma unroll
                for (int yr = 0; yr < 10; ++yr) {
                    const int gy = min(y0 + yr, IN - 1);
                    const int off = gz * IN2 + gy * IN;
                    float f0 = p0[off], f1 = p1[off];
                    dst[(zr * 10 + yr) * RS] = ((unsigned)f2bf(f1) << 16) | f2bf(f0);
                }
            }
        }
    }
    __syncthreads();

    float t1[4] = {0, 0, 0, 0};
    float t2[4] = {0, 0, 0, 0};

    if (z < OUTD) {
        const int ymax = min(8, OUTD - y0);
        #pragma unroll
        for (int y = 0; y < 8; ++y) {
            #pragma unroll
            for (int xt = 0; xt < 3; ++xt) {
                f32x4 aH, aL;
                #pragma unroll
                for (int i = 0; i < 4; ++i) { aH[i] = bias_r[i]; aL[i] = 0.f; }
                #pragma unroll
                for (int c = 0; c < 7; ++c) {
                    i32x4 bd = *(const i32x4*)(bc[c] + y * (RS * 4) + xt * 256);
                    v8s B = __builtin_bit_cast(v8s, bd);
                    aH = __builtin_amdgcn_mfma_f32_16x16x32_bf16(
                        __builtin_bit_cast(v8s, Ah[c]), B, aH, 0, 0, 0);
                    aL = __builtin_amdgcn_mfma_f32_16x16x32_bf16(
                        __builtin_bit_cast(v8s, Al[c]), B, aL, 0, 0, 0);
                }
                const bool ok = (y < ymax) && (xt * 16 + n < OUTD);
                #pragma unroll
                for (int i = 0; i < 4; ++i) {
                    float v = aH[i] + aL[i];             // bias already in aH
                    float u = fminf(fmaxf(v + 3.0f, 0.0f), 6.0f);
                    float hs = v * u * (1.0f / 6.0f);
                    float hm = ok ? hs : 0.f;
                    t1[i] += hm;
                    t2[i] = fmaf(hm, hm, t2[i]);
                }
            }
        }
    }

    // reduce over the 16 col-lanes (n); channel is per-(kq, i, coh)
    #pragma unroll
    for (int i = 0; i < 4; ++i) {
        #pragma unroll
        for (int k = 1; k < 16; k <<= 1) {
            t1[i] += __shfl_xor(t1[i], k, 64);
            t2[i] += __shfl_xor(t2[i], k, 64);
        }
    }
    if (n == 0) {
        #pragma unroll
        for (int i = 0; i < 4; ++i) {
            const int co = coh * 16 + kq * 4 + i;
            atomicAdd(&s1b[co], t1[i]);
            atomicAdd(&s2b[co], t2[i]);
        }
    }
    __syncthreads();
    if (tid < 32)       atomicAdd(&ws1[b * 32 + tid], s1b[tid]);
    else if (tid < 64)  atomicAdd(&ws2[b * 32 + (tid - 32)], s2b[tid - 32]);
}

__global__ __launch_bounds__(512) void gn_finalize(
    const float* __restrict__ ws1, const float* __restrict__ ws2,
    const float* __restrict__ gnw, const float* __restrict__ gnb,
    float* __restrict__ out)
{
    int tid = threadIdx.x;
    int c = tid & 31;
    float s1 = ws1[tid], s2 = ws2[tid];
    float g1 = s1, g2 = s2;
    #pragma unroll
    for (int k = 1; k < 8; k <<= 1) {
        g1 += __shfl_xor(g1, k, 64);
        g2 += __shfl_xor(g2, k, 64);
    }
    const float Nsp  = 46.0f * 46.0f * 46.0f;
    const float invN = 1.0f / (8.0f * Nsp);
    float mean = g1 * invN;
    float var  = fmaxf(g2 * invN - mean * mean, 0.0f);
    float rstd = rsqrtf(var + 1e-5f);
    float mc   = s1 * (1.0f / Nsp);
    out[tid] = (mc - mean) * rstd * gnw[c] + gnb[c];
}

extern "C" void kernel_launch(void* const* d_in, const int* in_sizes, int n_in,
                              void* d_out, int out_size, void* d_ws, size_t ws_size,
                              hipStream_t stream) {
    const float* x    = (const float*)d_in[0];
    const float* w    = (const float*)d_in[1];
    const float* bias = (const float*)d_in[2];
    const float* gnw  = (const float*)d_in[3];
    const float* gnb  = (const float*)d_in[4];
    float* out = (float*)d_out;
    float* ws1 = (float*)d_ws;
    float* ws2 = ws1 + 512;
    unsigned* wpk = (unsigned*)d_ws + WPK_OFF;   // 7168 dwords

    pack_weights<<<dim3(7), dim3(256), 0, stream>>>(w, wpk, ws1);
    conv_hs_mfma<<<dim3(16 * 12 * 6), dim3(512), 0, stream>>>(x, wpk, bias, ws1, ws2);
    gn_finalize<<<dim3(1), dim3(512), 0, stream>>>(ws1, ws2, gnw, gnb, out);
}

// Round 6
// 183.931 us; speedup vs baseline: 1.4071x; 1.4071x over previous
//
#include <hip/hip_runtime.h>

// Conv3d(8->32, k=3, VALID) + bias + HardSwish + GroupNorm(4) + mean pool.
// R9 = R8 with the register cap fixed. R8's counters: VGPR_Count=64 (!) --
// __launch_bounds__(512,4) was taken as an 8-waves/EU target (cap 512/8=64),
// so the 56-VGPR A-table + everything else spilled to scratch: WRITE_SIZE
// 268 MB, FETCH 187 MB (~350 MB scratch round-trip = the whole 181 us).
// Fix: __launch_bounds__(512, 2) -> cap 256 VGPRs; expect ~110-130 alloc,
// zero scratch. Structure unchanged from R8:
//  - 16x16x32 MFMA, co split across waves (8 waves = 4z x 2coh)
//  - A-table = 7 chunks x 2 (hi/lo) x 4 regs = 56 VGPRs, resident
//  - B fragment: K=32 = 4 taps x 8 ci; lane reads 8 ci at one tap = one
//    contiguous ds_read_b128 (R8 counters confirmed: bank conflicts 2.84M->0.42M)
//  - full unroll 8y x 3xt: LDS addresses fold into offset: immediates
//  - epilogue: 32 shuffles; pack_weights also zeroes ws (no memset dispatch)

#define IN 48
#define IN2 2304
#define IN3 110592
#define OUTD 46
#define RS 200            // row stride in dwords (48*4 used + 8 pad for masked overread)
#define NROW 60           // 6 z-rows x 10 y-rows
#define WPK_OFF 1024      // dword offset of packed-weight table inside ws

typedef short v8s    __attribute__((ext_vector_type(8)));
typedef float f32x4  __attribute__((ext_vector_type(4)));
typedef int   i32x4  __attribute__((ext_vector_type(4)));

__device__ __forceinline__ unsigned short f2bf(float f) {
    unsigned u = __builtin_bit_cast(unsigned, f);
    return (unsigned short)((u + 0x7fffu + ((u >> 16) & 1u)) >> 16);   // RNE
}
__device__ __forceinline__ float bf2f(unsigned short h) {
    unsigned u = ((unsigned)h) << 16;
    return __builtin_bit_cast(float, u);
}

// A fragments for 16x16x32, co-split. Layout: [coh][hl][c 0..6][lane][4 dw].
// Lane: co_local = lane&15, kq = lane>>4 -> tap tau = 4c+kq; dword j = ci pair
// (2j lo, 2j+1 hi). tau>=27 -> zero. Also zeroes ws1/ws2 (gid<1024).
__global__ __launch_bounds__(256) void pack_weights(
    const float* __restrict__ w, unsigned* __restrict__ wpk,
    float* __restrict__ wsz)
{
    int gid = blockIdx.x * 256 + threadIdx.x;
    if (gid < 1024) wsz[gid] = 0.f;
    if (gid >= 1792) return;
    int lane = gid & 63;
    int rest = gid >> 6;          // 0..27
    int c   = rest % 7;
    int hl  = (rest / 7) & 1;     // 0 = hi bf16, 1 = lo (residual)
    int coh = rest / 14;
    int n = lane & 15, kq = lane >> 4;
    int co  = coh * 16 + n;
    int tau = 4 * c + kq;
    unsigned o[4];
    #pragma unroll
    for (int j = 0; j < 4; ++j) {
        if (tau >= 27) { o[j] = 0u; continue; }
        float w0 = w[(co * 8 + 2 * j) * 27 + tau];
        float w1 = w[(co * 8 + 2 * j + 1) * 27 + tau];
        unsigned short b0 = f2bf(w0), b1 = f2bf(w1);
        if (hl) {
            b0 = f2bf(w0 - bf2f(b0));
            b1 = f2bf(w1 - bf2f(b1));
        }
        o[j] = ((unsigned)b1 << 16) | b0;
    }
    *(i32x4*)(wpk + (((coh * 2 + hl) * 7 + c) * 64 + lane) * 4) =
        (i32x4){(int)o[0], (int)o[1], (int)o[2], (int)o[3]};
}

__global__ __launch_bounds__(512, 2) void conv_hs_mfma(
    const float* __restrict__ x, const unsigned* __restrict__ wpk,
    const float* __restrict__ bias, float* __restrict__ ws1, float* __restrict__ ws2)
{
    __shared__ unsigned xdw[NROW * RS];   // 48 KB: [row 60][e*4 + cipair] linear
    __shared__ float s1b[32], s2b[32];

    const int tid  = threadIdx.x;
    const int lane = tid & 63;
    const int wv   = tid >> 6;          // 0..7
    const int zw   = wv & 3;            // z offset within tile
    const int coh  = wv >> 2;           // co half (0: co 0-15, 1: co 16-31)
    const int n    = lane & 15;         // A row (co_local) / B col (x)
    const int kq   = lane >> 4;         // k-quarter -> tap 4c+kq

    const int blk = blockIdx.x;
    const int b   = blk / 72;
    const int r0  = blk - b * 72;
    const int zb  = r0 / 6;
    const int yb  = r0 - zb * 6;
    const int z0  = zb * 4, y0 = yb * 8;
    const int z   = z0 + zw;

    if (tid < 32)      s1b[tid] = 0.f;
    else if (tid < 64) s2b[tid - 32] = 0.f;

    // A fragments: 14 coalesced 16B loads; 56 VGPRs, stay resident.
    i32x4 Ah[7], Al[7];
    #pragma unroll
    for (int c = 0; c < 7; ++c) {
        Ah[c] = *(const i32x4*)(wpk + (((coh * 2 + 0) * 7 + c) * 64 + lane) * 4);
        Al[c] = *(const i32x4*)(wpk + (((coh * 2 + 1) * 7 + c) * 64 + lane) * 4);
    }

    // C/D layout (16x16): col = n, row(co_local) = kq*4 + i
    float bias_r[4];
    #pragma unroll
    for (int i = 0; i < 4; ++i)
        bias_r[i] = bias[coh * 16 + kq * 4 + i];

    // Per-lane LDS base per chunk: tau = min(4c+kq, 26) (pad slot -> A=0).
    const char* bc[7];
    #pragma unroll
    for (int c = 0; c < 7; ++c) {
        int tau = 4 * c + kq; if (tau > 26) tau = 26;
        const int toff = ((tau / 9) * 10 + ((tau % 9) / 3)) * (RS * 4)
                       + (tau % 3) * 16;
        bc[c] = (const char*)xdw + zw * (10 * RS * 4) + n * 16 + toff;
    }

    // ---- stage x tile, bf16 ci-pair packed, linear layout ----
    {
        const int q  = tid & 3;
        const int zh = (tid >> 2) & 1;
        const int e  = tid >> 3;          // 0..63, active < 48
        if (e < 48) {
            const float* p0 = x + (b * 8 + 2 * q) * IN3 + e;
            const float* p1 = p0 + IN3;
            unsigned* dst = xdw + e * 4 + q;
            #pragma unroll
            for (int zr2 = 0; zr2 < 3; ++zr2) {
                const int zr = zh * 3 + zr2;
                const int gz = min(z0 + zr, IN - 1);
                #pragma unroll
                for (int yr = 0; yr < 10; ++yr) {
                    const int gy = min(y0 + yr, IN - 1);
                    const int off = gz * IN2 + gy * IN;
                    float f0 = p0[off], f1 = p1[off];
                    dst[(zr * 10 + yr) * RS] = ((unsigned)f2bf(f1) << 16) | f2bf(f0);
                }
            }
        }
    }
    __syncthreads();

    float t1[4] = {0, 0, 0, 0};
    float t2[4] = {0, 0, 0, 0};

    if (z < OUTD) {
        const int ymax = min(8, OUTD - y0);
        #pragma unroll
        for (int y = 0; y < 8; ++y) {
            #pragma unroll
            for (int xt = 0; xt < 3; ++xt) {
                f32x4 aH, aL;
                #pragma unroll
                for (int i = 0; i < 4; ++i) { aH[i] = bias_r[i]; aL[i] = 0.f; }
                #pragma unroll
                for (int c = 0; c < 7; ++c) {
                    i32x4 bd = *(const i32x4*)(bc[c] + y * (RS * 4) + xt * 256);
                    v8s B = __builtin_bit_cast(v8s, bd);
                    aH = __builtin_amdgcn_mfma_f32_16x16x32_bf16(
                        __builtin_bit_cast(v8s, Ah[c]), B, aH, 0, 0, 0);
                    aL = __builtin_amdgcn_mfma_f32_16x16x32_bf16(
                        __builtin_bit_cast(v8s, Al[c]), B, aL, 0, 0, 0);
                }
                const bool ok = (y < ymax) && (xt * 16 + n < OUTD);
                #pragma unroll
                for (int i = 0; i < 4; ++i) {
                    float v = aH[i] + aL[i];             // bias already in aH
                    float u = fminf(fmaxf(v + 3.0f, 0.0f), 6.0f);
                    float hs = v * u * (1.0f / 6.0f);
                    float hm = ok ? hs : 0.f;
                    t1[i] += hm;
                    t2[i] = fmaf(hm, hm, t2[i]);
                }
            }
        }
    }

    // reduce over the 16 col-lanes (n); channel is per-(kq, i, coh)
    #pragma unroll
    for (int i = 0; i < 4; ++i) {
        #pragma unroll
        for (int k = 1; k < 16; k <<= 1) {
            t1[i] += __shfl_xor(t1[i], k, 64);
            t2[i] += __shfl_xor(t2[i], k, 64);
        }
    }
    if (n == 0) {
        #pragma unroll
        for (int i = 0; i < 4; ++i) {
            const int co = coh * 16 + kq * 4 + i;
            atomicAdd(&s1b[co], t1[i]);
            atomicAdd(&s2b[co], t2[i]);
        }
    }
    __syncthreads();
    if (tid < 32)       atomicAdd(&ws1[b * 32 + tid], s1b[tid]);
    else if (tid < 64)  atomicAdd(&ws2[b * 32 + (tid - 32)], s2b[tid - 32]);
}

__global__ __launch_bounds__(512) void gn_finalize(
    const float* __restrict__ ws1, const float* __restrict__ ws2,
    const float* __restrict__ gnw, const float* __restrict__ gnb,
    float* __restrict__ out)
{
    int tid = threadIdx.x;
    int c = tid & 31;
    float s1 = ws1[tid], s2 = ws2[tid];
    float g1 = s1, g2 = s2;
    #pragma unroll
    for (int k = 1; k < 8; k <<= 1) {
        g1 += __shfl_xor(g1, k, 64);
        g2 += __shfl_xor(g2, k, 64);
    }
    const float Nsp  = 46.0f * 46.0f * 46.0f;
    const float invN = 1.0f / (8.0f * Nsp);
    float mean = g1 * invN;
    float var  = fmaxf(g2 * invN - mean * mean, 0.0f);
    float rstd = rsqrtf(var + 1e-5f);
    float mc   = s1 * (1.0f / Nsp);
    out[tid] = (mc - mean) * rstd * gnw[c] + gnb[c];
}

extern "C" void kernel_launch(void* const* d_in, const int* in_sizes, int n_in,
                              void* d_out, int out_size, void* d_ws, size_t ws_size,
                              hipStream_t stream) {
    const float* x    = (const float*)d_in[0];
    const float* w    = (const float*)d_in[1];
    const float* bias = (const float*)d_in[2];
    const float* gnw  = (const float*)d_in[3];
    const float* gnb  = (const float*)d_in[4];
    float* out = (float*)d_out;
    float* ws1 = (float*)d_ws;
    float* ws2 = ws1 + 512;
    unsigned* wpk = (unsigned*)d_ws + WPK_OFF;   // 7168 dwords

    pack_weights<<<dim3(7), dim3(256), 0, stream>>>(w, wpk, ws1);
    conv_hs_mfma<<<dim3(16 * 12 * 6), dim3(512), 0, stream>>>(x, wpk, bias, ws1, ws2);
    gn_finalize<<<dim3(1), dim3(512), 0, stream>>>(ws1, ws2, gnw, gnb, out);
}